// Round 6
// baseline (57.506 us; speedup 1.0000x reference)
//
#include <hip/hip_runtime.h>

// Problem constants (from reference): B=64, H=W=512, 256 zones.
#define NZ    256
#define NB    64
#define NPIX  (512 * 512)

// Pass-1 geometry: 32 elems/thread -> 2048 blocks, 1 KB partial table each.
#define EPT1  32
#define CHUNK1 (256 * EPT1)        // 8192 px per block
#define BPB1  (NPIX / CHUNK1)      // 32 blocks per batch
#define NBLK1 (NB * BPB1)          // 2048

// Replicated LDS table: 4 copies, +8-word stride so copy c's zone z lands on
// bank (8c+z)%32 -> copies are bank-shifted. copy = (lane&63)>>4 gives each
// 16-lane quarter-wave a private copy -> same-address multiplicity within one
// ds-atomic instruction drops from ~3-4 to ~1-2.
#define NCPY  4
#define NZP   264                  // NZ + 8

// Pass-3 geometry: 16 elems/thread -> 4096 blocks (~11us, near stream floor).
#define CHUNK3 (256 * 16)
#define BPB3  (NPIX / CHUNK3)      // 64
#define NBLK3 (NB * BPB3)          // 4096

__device__ __forceinline__ unsigned umax2(unsigned a, unsigned b) { return a > b ? a : b; }

// Monotonic float->unsigned encoding: preserves total order.
// enc()==0 only for bits 0xFFFFFFFF (a NaN) -> safe "empty" sentinel; dec(0)=NaN.
__device__ __forceinline__ unsigned enc(float f) {
    unsigned b = __float_as_uint(f);
    return b ^ ((b & 0x80000000u) ? 0xFFFFFFFFu : 0x80000000u);
}
__device__ __forceinline__ float dec(unsigned u) {
    unsigned b = (u & 0x80000000u) ? (u ^ 0x80000000u) : ~u;
    return __uint_as_float(b);
}

// Pass 1: per-block segmax over 8192 px into a 4-way replicated LDS table.
// Model from R2-R5 (all ~43-45us regardless of DS lane traffic): cost is
// ~70cyc per scattered ds-ATOMIC INSTRUCTION (1024/CU, fixed at 1 per 64 px).
// This round tests whether same-address RMW serialization is the bulk of the
// 70cyc by giving each 16-lane group a private, bank-shifted table copy.
// Filter kept from R5 (costs ~0, thins RMW lanes).
__global__ __launch_bounds__(256) void segmax_part(
        const float* __restrict__ inp, const int* __restrict__ zones,
        unsigned* __restrict__ part) {
    __shared__ unsigned sm[NCPY * NZP];
    const int t = threadIdx.x;
    for (int i = t; i < NCPY * NZP; i += 256) sm[i] = 0u;
    __syncthreads();

    const int cbase = ((t & 63) >> 4) * NZP;  // private copy per quarter-wave

    const int batch = blockIdx.x / BPB1;
    const int chunk = blockIdx.x % BPB1;
    const long base = (long)batch * NPIX + (long)chunk * CHUNK1;
    const float4* in4 = (const float4*)(inp + base);
    const int4*   z4  = (const int4*)(zones + base);

#pragma unroll
    for (int h = 0; h < EPT1 / 4; ++h) {
        float4 v = in4[h * 256 + t];
        int4   z = z4[h * 256 + t];
        unsigned e0 = enc(v.x), e1 = enc(v.y), e2 = enc(v.z), e3 = enc(v.w);
        const int i0 = cbase + z.x, i1 = cbase + z.y, i2 = cbase + z.z, i3 = cbase + z.w;
        unsigned c0 = sm[i0], c1 = sm[i1], c2 = sm[i2], c3 = sm[i3];
        if (e0 > c0) atomicMax(&sm[i0], e0);
        if (e1 > c1) atomicMax(&sm[i1], e1);
        if (e2 > c2) atomicMax(&sm[i2], e2);
        if (e3 > c3) atomicMax(&sm[i3], e3);
    }
    __syncthreads();

    unsigned m = umax2(umax2(sm[t], sm[NZP + t]),
                       umax2(sm[2 * NZP + t], sm[3 * NZP + t]));
    part[(long)blockIdx.x * NZ + t] = m;  // coalesced 1 KB store
}

// Pass 2: one block per batch; thread t max-combines zone t over the batch's
// 32 chunk tables (stride-NZ reads coalesce across threads) and stores the
// DECODED float (empty zone -> dec(0)=NaN, matches no pixel).
__global__ __launch_bounds__(256) void segmax_reduce(
        const unsigned* __restrict__ part, float* __restrict__ segf) {
    const int t = threadIdx.x;
    const int batch = blockIdx.x;
    const unsigned* p = part + (long)batch * BPB1 * NZ;
    unsigned m = 0u;
#pragma unroll 8
    for (int c = 0; c < BPB1; ++c) m = umax2(m, p[c * NZ + t]);
    segf[batch * NZ + t] = dec(m);
}

// Pass 3: mask = (x == segmax[zone]) as int32 0/1; per-block partial count to
// a private slot (contended global atomicAdd was the 192us R1 bug).
__global__ __launch_bounds__(256) void mask_kernel(
        const float* __restrict__ inp, const int* __restrict__ zones,
        const float* __restrict__ segf,
        int* __restrict__ mask, int* __restrict__ partial) {
    __shared__ float smax[NZ];
    __shared__ int wsum[4];
    const int t = threadIdx.x;

    const int batch = blockIdx.x / BPB3;
    const int chunk = blockIdx.x % BPB3;

    smax[t] = segf[batch * NZ + t];
    __syncthreads();

    const long base = (long)batch * NPIX + (long)chunk * CHUNK3;
    const float4* in4 = (const float4*)(inp + base);
    const int4*   z4  = (const int4*)(zones + base);
    int4* m4 = (int4*)(mask + base);

    int c = 0;
#pragma unroll
    for (int it = 0; it < 4; ++it) {
        float4 v = in4[it * 256 + t];
        int4   z = z4[it * 256 + t];
        int4 m;
        m.x = (v.x == smax[z.x]) ? 1 : 0;
        m.y = (v.y == smax[z.y]) ? 1 : 0;
        m.z = (v.z == smax[z.z]) ? 1 : 0;
        m.w = (v.w == smax[z.w]) ? 1 : 0;
        m4[it * 256 + t] = m;
        c += m.x + m.y + m.z + m.w;
    }

#pragma unroll
    for (int off = 32; off; off >>= 1) c += __shfl_down(c, off);
    if ((t & 63) == 0) wsum[t >> 6] = c;
    __syncthreads();
    if (t == 0) partial[blockIdx.x] = wsum[0] + wsum[1] + wsum[2] + wsum[3];
}

// Pass 4: single block sums the 4096 partials into the output counter.
__global__ __launch_bounds__(256) void count_kernel(
        const int* __restrict__ partial, int n, int* __restrict__ count) {
    __shared__ int wsum[4];
    const int t = threadIdx.x;
    int c = 0;
    for (int i = t; i < n; i += 256) c += partial[i];
#pragma unroll
    for (int off = 32; off; off >>= 1) c += __shfl_down(c, off);
    if ((t & 63) == 0) wsum[t >> 6] = c;
    __syncthreads();
    if (t == 0) *count = wsum[0] + wsum[1] + wsum[2] + wsum[3];
}

extern "C" void kernel_launch(void* const* d_in, const int* in_sizes, int n_in,
                              void* d_out, int out_size, void* d_ws, size_t ws_size,
                              hipStream_t stream) {
    const float* inp   = (const float*)d_in[0];
    const int*   zones = (const int*)d_in[1];
    int*         out   = (int*)d_out;   // [B*NPIX] mask + [1] n_centers, int32

    // Workspace layout (all fully overwritten every call -> no memset needed,
    // deterministic under graph replay):
    //   part   : NBLK1*NZ u32 = 2 MB
    //   segf   : NB*NZ   f32  = 64 KB
    //   partial: NBLK3   i32  = 16 KB
    unsigned* part    = (unsigned*)d_ws;
    float*    segf    = (float*)((char*)d_ws + (size_t)NBLK1 * NZ * 4);
    int*      partial = (int*)((char*)d_ws + (size_t)NBLK1 * NZ * 4 + (size_t)NB * NZ * 4);

    const long nmask = (long)NB * NPIX;  // == out_size - 1

    segmax_part  <<<NBLK1, 256, 0, stream>>>(inp, zones, part);
    segmax_reduce<<<NB,    256, 0, stream>>>(part, segf);
    mask_kernel  <<<NBLK3, 256, 0, stream>>>(inp, zones, segf, out, partial);
    count_kernel <<<1,     256, 0, stream>>>(partial, NBLK3, out + nmask);
}

// Round 7
// 56.933 us; speedup vs baseline: 1.0101x; 1.0101x over previous
//
#include <hip/hip_runtime.h>

// Problem constants (from reference): B=64, H=W=512, 256 zones.
#define NZ    256
#define NB    64
#define NPIX  (512 * 512)

// Pass-1 geometry: 2048 blocks x 256 thr; each block 8192 px; each wave owns
// 2048 px = 8 steps x 256 px, staged through a PRIVATE double buffer.
#define EPT1    32
#define CHUNK1  (256 * EPT1)       // 8192 px per block
#define BPB1    (NPIX / CHUNK1)    // 32 blocks per batch
#define NBLK1   (NB * BPB1)        // 2048
#define STEP_PX 256                // px per wave per step (1KB inp + 1KB zones)
#define NSTEP   (CHUNK1 / 4 / STEP_PX)  // 8

// Pass-3 geometry: 16 elems/thread -> 4096 blocks (near stream floor).
#define CHUNK3 (256 * 16)
#define BPB3  (NPIX / CHUNK3)      // 64
#define NBLK3 (NB * BPB3)          // 4096

__device__ __forceinline__ unsigned umax2(unsigned a, unsigned b) { return a > b ? a : b; }

// Monotonic float->unsigned encoding: preserves total order.
// enc()==0 only for bits 0xFFFFFFFF (a NaN) -> safe "empty" sentinel; dec(0)=NaN.
__device__ __forceinline__ unsigned enc(float f) {
    unsigned b = __float_as_uint(f);
    return b ^ ((b & 0x80000000u) ? 0xFFFFFFFFu : 0x80000000u);
}
__device__ __forceinline__ float dec(unsigned u) {
    unsigned b = (u & 0x80000000u) ? (u ^ 0x80000000u) : ~u;
    return __uint_as_float(b);
}

// Async global->LDS, 16B per lane. Dest is wave-uniform base + lane*16 (we pass
// base+lane*16; HW uses lane0's base), source address is per-lane.
__device__ __forceinline__ void gload16(const void* g, void* l) {
    __builtin_amdgcn_global_load_lds(
        (const __attribute__((address_space(1))) void*)g,
        (__attribute__((address_space(3))) void*)l, 16, 0, 0);
}

// Pass 1: per-block LDS segmax over 8192 px.
// R2-R6 post-mortem: segmax was memory-LATENCY-bound (only ~2-8 loads in
// flight/wave; 1.5 TB/s = in-flight/latency by Little's law), DS work was
// always hidden. Fix: per-WAVE double-buffered global_load_lds staging with
// counted vmcnt(2) waits and NO block barrier in the loop -> 2KB in flight
// per wave (64KB/CU) -> HBM-bound. Consume from LDS via ds_read_b128; keep
// R5's fresh-filter LDS atomics (race-safe: a true max beats every
// intermediate value, so its atomic always fires).
__global__ __launch_bounds__(256) void segmax_part(
        const float* __restrict__ inp, const int* __restrict__ zones,
        unsigned* __restrict__ part) {
    __shared__ unsigned smax[NZ];
    __shared__ uint4 stage4[4][2][128];  // [wave][buf][2KB: 1KB inp | 1KB zones]
    const int t = threadIdx.x;
    const int lane = t & 63, wave = t >> 6;
    smax[t] = 0u;
    __syncthreads();

    const int batch = blockIdx.x / BPB1;
    const int chunk = blockIdx.x % BPB1;
    const long base = (long)batch * NPIX + (long)chunk * CHUNK1 + (long)wave * (CHUNK1 / 4);
    const float* ginp = inp + base;
    const int*   gzon = zones + base;

    unsigned char* bufA = (unsigned char*)&stage4[wave][0][0];
    unsigned char* bufB = (unsigned char*)&stage4[wave][1][0];

    // Prologue: stage steps 0 and 1 (4 loads in flight).
    gload16(ginp + 0 * STEP_PX + 4 * lane, bufA + 16 * lane);
    gload16(gzon + 0 * STEP_PX + 4 * lane, bufA + 1024 + 16 * lane);
    gload16(ginp + 1 * STEP_PX + 4 * lane, bufB + 16 * lane);
    gload16(gzon + 1 * STEP_PX + 4 * lane, bufB + 1024 + 16 * lane);

    unsigned char* cur = bufA;
    unsigned char* nxt = bufB;
#pragma unroll 1
    for (int s = 0; s < NSTEP - 1; ++s) {
        asm volatile("s_waitcnt vmcnt(2)" ::: "memory");  // step s arrived
        __builtin_amdgcn_sched_barrier(0);
        float4 v = ((const float4*)cur)[lane];
        int4   z = ((const int4*)(cur + 1024))[lane];
        unsigned e0 = enc(v.x), e1 = enc(v.y), e2 = enc(v.z), e3 = enc(v.w);
        unsigned c0 = smax[z.x], c1 = smax[z.y], c2 = smax[z.z], c3 = smax[z.w];
        if (e0 > c0) atomicMax(&smax[z.x], e0);
        if (e1 > c1) atomicMax(&smax[z.y], e1);
        if (e2 > c2) atomicMax(&smax[z.z], e2);
        if (e3 > c3) atomicMax(&smax[z.w], e3);
        __builtin_amdgcn_sched_barrier(0);
        if (s + 2 < NSTEP) {  // refill the buffer just consumed
            gload16(ginp + (s + 2) * STEP_PX + 4 * lane, cur + 16 * lane);
            gload16(gzon + (s + 2) * STEP_PX + 4 * lane, cur + 1024 + 16 * lane);
        }
        unsigned char* tmp = cur; cur = nxt; nxt = tmp;
    }
    asm volatile("s_waitcnt vmcnt(0)" ::: "memory");  // last step
    __builtin_amdgcn_sched_barrier(0);
    {
        float4 v = ((const float4*)cur)[lane];
        int4   z = ((const int4*)(cur + 1024))[lane];
        unsigned e0 = enc(v.x), e1 = enc(v.y), e2 = enc(v.z), e3 = enc(v.w);
        unsigned c0 = smax[z.x], c1 = smax[z.y], c2 = smax[z.z], c3 = smax[z.w];
        if (e0 > c0) atomicMax(&smax[z.x], e0);
        if (e1 > c1) atomicMax(&smax[z.y], e1);
        if (e2 > c2) atomicMax(&smax[z.z], e2);
        if (e3 > c3) atomicMax(&smax[z.w], e3);
    }
    __syncthreads();
    part[(long)blockIdx.x * NZ + t] = smax[t];  // coalesced 1 KB store
}

// Pass 2: one block per batch; thread t max-combines zone t over the batch's
// 32 chunk tables and stores the DECODED float (empty zone -> NaN).
__global__ __launch_bounds__(256) void segmax_reduce(
        const unsigned* __restrict__ part, float* __restrict__ segf) {
    const int t = threadIdx.x;
    const int batch = blockIdx.x;
    const unsigned* p = part + (long)batch * BPB1 * NZ;
    unsigned m = 0u;
#pragma unroll 8
    for (int c = 0; c < BPB1; ++c) m = umax2(m, p[c * NZ + t]);
    segf[batch * NZ + t] = dec(m);
}

// Pass 3: mask = (x == segmax[zone]) as int32 0/1; per-block partial count to
// a private slot (contended global atomicAdd was the 192us R1 bug).
__global__ __launch_bounds__(256) void mask_kernel(
        const float* __restrict__ inp, const int* __restrict__ zones,
        const float* __restrict__ segf,
        int* __restrict__ mask, int* __restrict__ partial) {
    __shared__ float smax[NZ];
    __shared__ int wsum[4];
    const int t = threadIdx.x;

    const int batch = blockIdx.x / BPB3;
    const int chunk = blockIdx.x % BPB3;

    smax[t] = segf[batch * NZ + t];
    __syncthreads();

    const long base = (long)batch * NPIX + (long)chunk * CHUNK3;
    const float4* in4 = (const float4*)(inp + base);
    const int4*   z4  = (const int4*)(zones + base);
    int4* m4 = (int4*)(mask + base);

    int c = 0;
#pragma unroll
    for (int it = 0; it < 4; ++it) {
        float4 v = in4[it * 256 + t];
        int4   z = z4[it * 256 + t];
        int4 m;
        m.x = (v.x == smax[z.x]) ? 1 : 0;
        m.y = (v.y == smax[z.y]) ? 1 : 0;
        m.z = (v.z == smax[z.z]) ? 1 : 0;
        m.w = (v.w == smax[z.w]) ? 1 : 0;
        m4[it * 256 + t] = m;
        c += m.x + m.y + m.z + m.w;
    }

#pragma unroll
    for (int off = 32; off; off >>= 1) c += __shfl_down(c, off);
    if ((t & 63) == 0) wsum[t >> 6] = c;
    __syncthreads();
    if (t == 0) partial[blockIdx.x] = wsum[0] + wsum[1] + wsum[2] + wsum[3];
}

// Pass 4: single block sums the 4096 partials into the output counter.
__global__ __launch_bounds__(256) void count_kernel(
        const int* __restrict__ partial, int n, int* __restrict__ count) {
    __shared__ int wsum[4];
    const int t = threadIdx.x;
    int c = 0;
    for (int i = t; i < n; i += 256) c += partial[i];
#pragma unroll
    for (int off = 32; off; off >>= 1) c += __shfl_down(c, off);
    if ((t & 63) == 0) wsum[t >> 6] = c;
    __syncthreads();
    if (t == 0) *count = wsum[0] + wsum[1] + wsum[2] + wsum[3];
}

extern "C" void kernel_launch(void* const* d_in, const int* in_sizes, int n_in,
                              void* d_out, int out_size, void* d_ws, size_t ws_size,
                              hipStream_t stream) {
    const float* inp   = (const float*)d_in[0];
    const int*   zones = (const int*)d_in[1];
    int*         out   = (int*)d_out;   // [B*NPIX] mask + [1] n_centers, int32

    // Workspace layout (all fully overwritten every call -> no memset needed,
    // deterministic under graph replay):
    //   part   : NBLK1*NZ u32 = 2 MB
    //   segf   : NB*NZ   f32  = 64 KB
    //   partial: NBLK3   i32  = 16 KB
    unsigned* part    = (unsigned*)d_ws;
    float*    segf    = (float*)((char*)d_ws + (size_t)NBLK1 * NZ * 4);
    int*      partial = (int*)((char*)d_ws + (size_t)NBLK1 * NZ * 4 + (size_t)NB * NZ * 4);

    const long nmask = (long)NB * NPIX;  // == out_size - 1

    segmax_part  <<<NBLK1, 256, 0, stream>>>(inp, zones, part);
    segmax_reduce<<<NB,    256, 0, stream>>>(part, segf);
    mask_kernel  <<<NBLK3, 256, 0, stream>>>(inp, zones, segf, out, partial);
    count_kernel <<<1,     256, 0, stream>>>(partial, NBLK3, out + nmask);
}

// Round 8
// 56.591 us; speedup vs baseline: 1.0162x; 1.0060x over previous
//
#include <hip/hip_runtime.h>

// Problem constants (from reference): B=64, H=W=512, 256 zones.
#define NZ    256
#define NB    64
#define NPIX  (512 * 512)

// Pass-1 geometry: 32 elems/thread -> 2048 blocks.
#define EPT1  32
#define CHUNK1 (256 * EPT1)        // 8192 px per block
#define BPB1  (NPIX / CHUNK1)      // 32 blocks per batch
#define NBLK1 (NB * BPB1)          // 2048

// Per-WAVE private LDS tables: 4 waves x 264 words (+8 stagger de-aliases
// banks across copies). R2-R7 post-mortem: every variant sharing ONE table
// across the block's 4 waves pinned at ~1.6 cy/px regardless of memory level
// (L3-resident replays equally slow), filter, replication-by-lane, staging.
// Hypothesis under test: cross-WAVE DS-op ordering on overlapping addresses
// serializes the block's waves; private-per-wave tables remove all overlap.
#define NZP   264                  // NZ + 8

// Pass-3 geometry: 16 elems/thread -> 4096 blocks (near stream floor).
#define CHUNK3 (256 * 16)
#define BPB3  (NPIX / CHUNK3)      // 64
#define NBLK3 (NB * BPB3)          // 4096

__device__ __forceinline__ unsigned umax2(unsigned a, unsigned b) { return a > b ? a : b; }

// Monotonic float->unsigned encoding: preserves total order.
// enc()==0 only for bits 0xFFFFFFFF (a NaN) -> safe "empty" sentinel; dec(0)=NaN.
__device__ __forceinline__ unsigned enc(float f) {
    unsigned b = __float_as_uint(f);
    return b ^ ((b & 0x80000000u) ? 0xFFFFFFFFu : 0x80000000u);
}
__device__ __forceinline__ float dec(unsigned u) {
    unsigned b = (u & 0x80000000u) ? (u ^ 0x80000000u) : ~u;
    return __uint_as_float(b);
}

// Pass 1: per-block segmax over 8192 px, each wave accumulating into its OWN
// 264-word LDS table (atomics still needed: lanes within a wave may collide
// on a zone, and ds atomics resolve that). Merge the 4 copies at the end.
__global__ __launch_bounds__(256) void segmax_part(
        const float* __restrict__ inp, const int* __restrict__ zones,
        unsigned* __restrict__ part) {
    __shared__ unsigned sm[4 * NZP];
    const int t = threadIdx.x;
    const int wave = t >> 6;
    for (int i = t; i < 4 * NZP; i += 256) sm[i] = 0u;
    __syncthreads();

    unsigned* mytab = &sm[wave * NZP];  // wave-private: zero cross-wave overlap

    const int batch = blockIdx.x / BPB1;
    const int chunk = blockIdx.x % BPB1;
    const long base = (long)batch * NPIX + (long)chunk * CHUNK1;
    const float4* in4 = (const float4*)(inp + base);
    const int4*   z4  = (const int4*)(zones + base);

#pragma unroll
    for (int h = 0; h < EPT1 / 4; ++h) {
        float4 v = in4[h * 256 + t];
        int4   z = z4[h * 256 + t];
        atomicMax(&mytab[z.x], enc(v.x));
        atomicMax(&mytab[z.y], enc(v.y));
        atomicMax(&mytab[z.z], enc(v.z));
        atomicMax(&mytab[z.w], enc(v.w));
    }
    __syncthreads();

    // Merge 4 wave-copies: thread t reads word t of each copy (lanes read
    // consecutive words -> conflict-free), stores zone t's block max.
    unsigned m = umax2(umax2(sm[t], sm[NZP + t]),
                       umax2(sm[2 * NZP + t], sm[3 * NZP + t]));
    part[(long)blockIdx.x * NZ + t] = m;  // coalesced 1 KB store
}

// Pass 2: one block per batch; thread t max-combines zone t over the batch's
// 32 chunk tables and stores the DECODED float (empty zone -> NaN).
__global__ __launch_bounds__(256) void segmax_reduce(
        const unsigned* __restrict__ part, float* __restrict__ segf) {
    const int t = threadIdx.x;
    const int batch = blockIdx.x;
    const unsigned* p = part + (long)batch * BPB1 * NZ;
    unsigned m = 0u;
#pragma unroll 8
    for (int c = 0; c < BPB1; ++c) m = umax2(m, p[c * NZ + t]);
    segf[batch * NZ + t] = dec(m);
}

// Pass 3: mask = (x == segmax[zone]) as int32 0/1; per-block partial count to
// a private slot (contended global atomicAdd was the 192us R1 bug).
__global__ __launch_bounds__(256) void mask_kernel(
        const float* __restrict__ inp, const int* __restrict__ zones,
        const float* __restrict__ segf,
        int* __restrict__ mask, int* __restrict__ partial) {
    __shared__ float smax[NZ];
    __shared__ int wsum[4];
    const int t = threadIdx.x;

    const int batch = blockIdx.x / BPB3;
    const int chunk = blockIdx.x % BPB3;

    smax[t] = segf[batch * NZ + t];
    __syncthreads();

    const long base = (long)batch * NPIX + (long)chunk * CHUNK3;
    const float4* in4 = (const float4*)(inp + base);
    const int4*   z4  = (const int4*)(zones + base);
    int4* m4 = (int4*)(mask + base);

    int c = 0;
#pragma unroll
    for (int it = 0; it < 4; ++it) {
        float4 v = in4[it * 256 + t];
        int4   z = z4[it * 256 + t];
        int4 m;
        m.x = (v.x == smax[z.x]) ? 1 : 0;
        m.y = (v.y == smax[z.y]) ? 1 : 0;
        m.z = (v.z == smax[z.z]) ? 1 : 0;
        m.w = (v.w == smax[z.w]) ? 1 : 0;
        m4[it * 256 + t] = m;
        c += m.x + m.y + m.z + m.w;
    }

#pragma unroll
    for (int off = 32; off; off >>= 1) c += __shfl_down(c, off);
    if ((t & 63) == 0) wsum[t >> 6] = c;
    __syncthreads();
    if (t == 0) partial[blockIdx.x] = wsum[0] + wsum[1] + wsum[2] + wsum[3];
}

// Pass 4: single block sums the 4096 partials into the output counter.
__global__ __launch_bounds__(256) void count_kernel(
        const int* __restrict__ partial, int n, int* __restrict__ count) {
    __shared__ int wsum[4];
    const int t = threadIdx.x;
    int c = 0;
    for (int i = t; i < n; i += 256) c += partial[i];
#pragma unroll
    for (int off = 32; off; off >>= 1) c += __shfl_down(c, off);
    if ((t & 63) == 0) wsum[t >> 6] = c;
    __syncthreads();
    if (t == 0) *count = wsum[0] + wsum[1] + wsum[2] + wsum[3];
}

extern "C" void kernel_launch(void* const* d_in, const int* in_sizes, int n_in,
                              void* d_out, int out_size, void* d_ws, size_t ws_size,
                              hipStream_t stream) {
    const float* inp   = (const float*)d_in[0];
    const int*   zones = (const int*)d_in[1];
    int*         out   = (int*)d_out;   // [B*NPIX] mask + [1] n_centers, int32

    // Workspace layout (all fully overwritten every call -> no memset needed,
    // deterministic under graph replay):
    //   part   : NBLK1*NZ u32 = 2 MB
    //   segf   : NB*NZ   f32  = 64 KB
    //   partial: NBLK3   i32  = 16 KB
    unsigned* part    = (unsigned*)d_ws;
    float*    segf    = (float*)((char*)d_ws + (size_t)NBLK1 * NZ * 4);
    int*      partial = (int*)((char*)d_ws + (size_t)NBLK1 * NZ * 4 + (size_t)NB * NZ * 4);

    const long nmask = (long)NB * NPIX;  // == out_size - 1

    segmax_part  <<<NBLK1, 256, 0, stream>>>(inp, zones, part);
    segmax_reduce<<<NB,    256, 0, stream>>>(part, segf);
    mask_kernel  <<<NBLK3, 256, 0, stream>>>(inp, zones, segf, out, partial);
    count_kernel <<<1,     256, 0, stream>>>(partial, NBLK3, out + nmask);
}